// Round 6
// baseline (265.594 us; speedup 1.0000x reference)
//
#include <hip/hip_runtime.h>
#include <stdint.h>

// ---------------------------------------------------------------------------
// GCN 2-layer encoder.  Key identity: with dinv[v] = 1/sqrt(deg_self(v)),
//   Agg(H)[v] = dinv[v] * ( sum_{(r->v) edges} dinv[r]*H[r]  +  dinv[v]*H[v] )
// so we pre-scale every GEMM output row by dinv[row] ("Hs") and the edge
// stream needs ONLY the source index (4 B/edge) -> minimal scatter traffic.
//   h1s = fp16(dinv .* (x @ W1)) ; g1 = fp16(relu(dinv .* AggSum(h1s) + b1))
//   h2s = fp16(dinv .* (g1 @ W2)); out = dinv .* AggSum(h2s) + b2   [fp32]
// ---------------------------------------------------------------------------

typedef _Float16 h2v   __attribute__((ext_vector_type(2)));
typedef _Float16 h4v   __attribute__((ext_vector_type(4)));
typedef _Float16 f16x8 __attribute__((ext_vector_type(8)));
typedef float    f32x4 __attribute__((ext_vector_type(4)));

// prep: cnt=0, W1/W2 -> fp16 transposed (rows = out-feature)
__global__ void k_prep(const float* __restrict__ W1, const float* __restrict__ W2,
                       _Float16* __restrict__ WT1, _Float16* __restrict__ WT2,
                       uint32_t* __restrict__ cnt, int n) {
    int i = blockIdx.x * blockDim.x + threadIdx.x;
    if (i < n) cnt[i] = 0u;                      // in-degree only (self loop implicit)
    if (i < 128 * 128) {
        int f = i >> 7, k = i & 127;
        WT1[i] = (_Float16)W1[k * 128 + f];
    }
    int j = i - 128 * 128;
    if (j >= 0 && j < 64 * 128) {
        int f = j >> 7, k = j & 127;
        WT2[j] = (_Float16)W2[k * 64 + f];
    }
}

__global__ void k_count(const int* __restrict__ col, uint32_t* __restrict__ cnt, int E) {
    int i = blockIdx.x * blockDim.x + threadIdx.x;
    if (i < E) atomicAdd(&cnt[__builtin_nontemporal_load(&col[i])], 1u);
}

// ---- exclusive scan of cnt -> rp; fill=rp; dinv = rsqrt(cnt+1) ----
constexpr int SCAN_CH = 512;

__global__ void k_scan_partial(const uint32_t* __restrict__ cnt, uint32_t* __restrict__ part, int n) {
    __shared__ uint32_t s[256];
    int t = threadIdx.x;
    int base = blockIdx.x * SCAN_CH;
    uint32_t v = 0;
    if (base + t       < n) v += cnt[base + t];
    if (base + t + 256 < n) v += cnt[base + t + 256];
    s[t] = v; __syncthreads();
    for (int off = 128; off > 0; off >>= 1) {
        if (t < off) s[t] += s[t + off];
        __syncthreads();
    }
    if (t == 0) part[blockIdx.x] = s[0];
}

__global__ void k_scan_top(uint32_t* __restrict__ part, uint32_t* __restrict__ total_out, int nb) {
    __shared__ uint32_t s[256];
    int t = threadIdx.x;
    uint32_t v = (t < nb) ? part[t] : 0u;
    s[t] = v; __syncthreads();
    for (int off = 1; off < 256; off <<= 1) {
        uint32_t u = (t >= off) ? s[t - off] : 0u;
        __syncthreads();
        s[t] += u;
        __syncthreads();
    }
    if (t < nb) part[t] = s[t] - v;          // exclusive
    if (t == nb - 1) *total_out = s[t];      // rp[n] = E
}

__global__ void k_scan_final(const uint32_t* __restrict__ cnt, const uint32_t* __restrict__ part,
                             uint32_t* __restrict__ rp, uint32_t* __restrict__ fill,
                             float* __restrict__ dinv, int n) {
    __shared__ uint32_t s[SCAN_CH];
    int t = threadIdx.x;
    int i = blockIdx.x * SCAN_CH + t;
    uint32_t v = (i < n) ? cnt[i] : 0u;
    s[t] = v; __syncthreads();
    for (int off = 1; off < SCAN_CH; off <<= 1) {
        uint32_t u = (t >= off) ? s[t - off] : 0u;
        __syncthreads();
        s[t] += u;
        __syncthreads();
    }
    if (i < n) {
        uint32_t ex = part[blockIdx.x] + s[t] - v;   // exclusive
        rp[i] = ex;
        fill[i] = ex;                                 // scatter cursor
        dinv[i] = rsqrtf((float)(v + 1u));            // deg incl. self loop
    }
}

// bucket-scatter: only the source index (4 B per edge)
__global__ void k_scatter(const int* __restrict__ row, const int* __restrict__ col,
                          uint32_t* __restrict__ fill, int* __restrict__ esrc, int E) {
    int i = blockIdx.x * blockDim.x + threadIdx.x;
    if (i >= E) return;
    int r = __builtin_nontemporal_load(&row[i]);
    int c = __builtin_nontemporal_load(&col[i]);
    uint32_t p = atomicAdd(&fill[c], 1u);
    esrc[p] = r;
}

// ---- MFMA GEMM: Hs[r] = fp16(dinv[r] * (X[r] @ W)), WT=[FOUT][128] fp16 ----
template <int FOUT, typename XT>
__global__ __launch_bounds__(256)
void k_gemm_mfma(const XT* __restrict__ X, const _Float16* __restrict__ WT,
                 const float* __restrict__ dinv, _Float16* __restrict__ H, int n) {
    constexpr int K  = 128;
    constexpr int KP = K + 8;           // pad -> conflict-free ds_read_b128
    constexpr int NT = FOUT / 16;
    __shared__ _Float16 Wl[FOUT * KP];

    const int tid = threadIdx.x;
    for (int i = tid; i < FOUT * (K / 8); i += 256) {
        int f = i / (K / 8), kc = i % (K / 8);
        *reinterpret_cast<f16x8*>(&Wl[f * KP + kc * 8]) =
            *reinterpret_cast<const f16x8*>(&WT[f * K + kc * 8]);
    }
    __syncthreads();

    const int wid  = tid >> 6;
    const int lane = tid & 63;
    const int col  = lane & 15;         // node within 16-tile
    const int krow = lane >> 4;         // k-chunk selector (0..3)
    const int node = blockIdx.x * 64 + wid * 16 + col;
    const int nld  = node < n ? node : n - 1;

    f32x4 acc[NT];
#pragma unroll
    for (int t = 0; t < NT; ++t) acc[t] = (f32x4){0.f, 0.f, 0.f, 0.f};

#pragma unroll
    for (int ks = 0; ks < 4; ++ks) {
        const int k0 = ks * 32 + krow * 8;
        f16x8 b;
        if constexpr (sizeof(XT) == 4) {
            float4 x0 = *reinterpret_cast<const float4*>(&X[(size_t)nld * K + k0]);
            float4 x1 = *reinterpret_cast<const float4*>(&X[(size_t)nld * K + k0 + 4]);
            b[0] = (_Float16)x0.x; b[1] = (_Float16)x0.y;
            b[2] = (_Float16)x0.z; b[3] = (_Float16)x0.w;
            b[4] = (_Float16)x1.x; b[5] = (_Float16)x1.y;
            b[6] = (_Float16)x1.z; b[7] = (_Float16)x1.w;
        } else {
            b = *reinterpret_cast<const f16x8*>(&X[(size_t)nld * K + k0]);
        }
#pragma unroll
        for (int t = 0; t < NT; ++t) {
            f16x8 a = *reinterpret_cast<const f16x8*>(&Wl[(t * 16 + col) * KP + k0]);
            acc[t] = __builtin_amdgcn_mfma_f32_16x16x32_f16(a, b, acc[t], 0, 0, 0);
        }
    }

    if (node < n) {
        const float dv = dinv[node];
#pragma unroll
        for (int t = 0; t < NT; ++t) {
            h4v hv;
            hv.x = (_Float16)(acc[t][0] * dv);
            hv.y = (_Float16)(acc[t][1] * dv);
            hv.z = (_Float16)(acc[t][2] * dv);
            hv.w = (_Float16)(acc[t][3] * dv);
            *reinterpret_cast<h4v*>(&H[(size_t)node * FOUT + t * 16 + krow * 4]) = hv;
        }
    }
}

// ---- pull agg F=128: g1 = fp16(relu(dinv[v]*(Σ Hs[src] + Hs[v]) + b1)) ----
__global__ void k_agg128(const _Float16* __restrict__ H, const uint32_t* __restrict__ rp,
                         const int* __restrict__ es, const float* __restrict__ dinv,
                         const float* __restrict__ bias, _Float16* __restrict__ out, int n) {
    int wave = (blockIdx.x * blockDim.x + threadIdx.x) >> 6;
    int lane = threadIdx.x & 63;
    if (wave >= n) return;
    const int v = wave;
    int p = (int)rp[v];
    const int e = (int)rp[v + 1];
    const int c0 = lane * 2;

    float ax = 0.f, ay = 0.f;
    for (; p + 8 <= e; p += 8) {
        int ss[8];
#pragma unroll
        for (int u = 0; u < 8; ++u) ss[u] = __builtin_nontemporal_load(&es[p + u]);
        h2v hh[8];
#pragma unroll
        for (int u = 0; u < 8; ++u)
            hh[u] = *reinterpret_cast<const h2v*>(&H[(size_t)ss[u] * 128 + c0]);
#pragma unroll
        for (int u = 0; u < 8; ++u) { ax += (float)hh[u].x; ay += (float)hh[u].y; }
    }
    if (p + 4 <= e) {
        int ss[4];
#pragma unroll
        for (int u = 0; u < 4; ++u) ss[u] = __builtin_nontemporal_load(&es[p + u]);
        h2v hh[4];
#pragma unroll
        for (int u = 0; u < 4; ++u)
            hh[u] = *reinterpret_cast<const h2v*>(&H[(size_t)ss[u] * 128 + c0]);
#pragma unroll
        for (int u = 0; u < 4; ++u) { ax += (float)hh[u].x; ay += (float)hh[u].y; }
        p += 4;
    }
    for (; p < e; ++p) {
        int s = __builtin_nontemporal_load(&es[p]);
        h2v h0 = *reinterpret_cast<const h2v*>(&H[(size_t)s * 128 + c0]);
        ax += (float)h0.x; ay += (float)h0.y;
    }
    // self loop (pre-scaled row) + epilogue
    h2v sv = *reinterpret_cast<const h2v*>(&H[(size_t)v * 128 + c0]);
    ax += (float)sv.x; ay += (float)sv.y;
    const float dv = dinv[v];
    ax = fmaxf(fmaf(dv, ax, bias[c0]), 0.f);
    ay = fmaxf(fmaf(dv, ay, bias[c0 + 1]), 0.f);
    h2v o; o.x = (_Float16)ax; o.y = (_Float16)ay;
    *reinterpret_cast<h2v*>(&out[(size_t)v * 128 + c0]) = o;
}

// ---- pull agg F=64: two 32-lane halves, stride-2 edges, fp32 out ----
__global__ void k_agg64(const _Float16* __restrict__ H, const uint32_t* __restrict__ rp,
                        const int* __restrict__ es, const float* __restrict__ dinv,
                        const float* __restrict__ bias, float* __restrict__ out, int n) {
    int wave = (blockIdx.x * blockDim.x + threadIdx.x) >> 6;
    int lane = threadIdx.x & 63;
    if (wave >= n) return;
    const int v = wave;
    const int half = lane >> 5;
    const int c0 = (lane & 31) * 2;
    int p = (int)rp[v] + half;
    const int e = (int)rp[v + 1];

    float ax = 0.f, ay = 0.f;
    for (; p + 6 < e; p += 8) {      // edges p, p+2, p+4, p+6 for this half
        int ss[4];
#pragma unroll
        for (int u = 0; u < 4; ++u) ss[u] = __builtin_nontemporal_load(&es[p + 2 * u]);
        h2v hh[4];
#pragma unroll
        for (int u = 0; u < 4; ++u)
            hh[u] = *reinterpret_cast<const h2v*>(&H[(size_t)ss[u] * 64 + c0]);
#pragma unroll
        for (int u = 0; u < 4; ++u) { ax += (float)hh[u].x; ay += (float)hh[u].y; }
    }
    for (; p < e; p += 2) {
        int s = __builtin_nontemporal_load(&es[p]);
        h2v h0 = *reinterpret_cast<const h2v*>(&H[(size_t)s * 64 + c0]);
        ax += (float)h0.x; ay += (float)h0.y;
    }
    ax += __shfl_xor(ax, 32);
    ay += __shfl_xor(ay, 32);
    if (lane < 32) {
        h2v sv = *reinterpret_cast<const h2v*>(&H[(size_t)v * 64 + c0]);
        ax += (float)sv.x; ay += (float)sv.y;
        const float dv = dinv[v];
        ax = fmaf(dv, ax, bias[c0]);
        ay = fmaf(dv, ay, bias[c0 + 1]);
        *reinterpret_cast<float2*>(&out[(size_t)v * 64 + c0]) = make_float2(ax, ay);
    }
}

extern "C" void kernel_launch(void* const* d_in, const int* in_sizes, int n_in,
                              void* d_out, int out_size, void* d_ws, size_t ws_size,
                              hipStream_t stream) {
    const float* x  = (const float*)d_in[0];
    const int*   ei = (const int*)d_in[1];
    const float* W1 = (const float*)d_in[2];
    const float* b1 = (const float*)d_in[3];
    const float* W2 = (const float*)d_in[4];
    const float* b2 = (const float*)d_in[5];
    float* out = (float*)d_out;

    const int hidden = in_sizes[3];                 // 128
    const int fin    = in_sizes[2] / hidden;        // 128
    const int n      = in_sizes[0] / fin;           // 50000
    const int E      = in_sizes[1] / 2;             // 800000
    const int* rowi = ei;                           // edge_index[0] = sources
    const int* coli = ei + E;                       // edge_index[1] = targets
    (void)n_in; (void)out_size; (void)ws_size;

    char* ws = (char*)d_ws;
    size_t off = 0;
    auto alloc = [&](size_t bytes) -> void* {
        off = (off + 255) & ~(size_t)255;
        void* p = ws + off;
        off += bytes;
        return p;
    };
    uint32_t*  cnt  = (uint32_t*) alloc((size_t)n * 4);
    uint32_t*  fill = (uint32_t*) alloc((size_t)n * 4);
    uint32_t*  rp   = (uint32_t*) alloc((size_t)(n + 1) * 4);
    float*     dinv = (float*)    alloc((size_t)n * 4);
    uint32_t*  part = (uint32_t*) alloc(1024);
    int*       esrc = (int*)      alloc((size_t)E * 4);
    _Float16*  h1   = (_Float16*) alloc((size_t)n * 128 * 2);  // reused as h2
    _Float16*  g1   = (_Float16*) alloc((size_t)n * 128 * 2);
    _Float16*  WT1  = (_Float16*) alloc(128 * 128 * 2);
    _Float16*  WT2  = (_Float16*) alloc(64 * 128 * 2);
    _Float16*  h2   = h1;

    const int nb256 = (n + 255) / 256;
    const int nbs   = (n + SCAN_CH - 1) / SCAN_CH;   // 98 (<=256 required)

    k_prep <<<nb256, 256, 0, stream>>>(W1, W2, WT1, WT2, cnt, n);
    k_count<<<(E + 255) / 256, 256, 0, stream>>>(coli, cnt, E);
    k_scan_partial<<<nbs, 256, 0, stream>>>(cnt, part, n);
    k_scan_top    <<<1, 256, 0, stream>>>(part, rp + n, nbs);
    k_scan_final  <<<nbs, SCAN_CH, 0, stream>>>(cnt, part, rp, fill, dinv, n);
    k_scatter<<<(E + 255) / 256, 256, 0, stream>>>(rowi, coli, fill, esrc, E);

    const int gb = (n + 63) / 64;
    k_gemm_mfma<128, float>   <<<gb, 256, 0, stream>>>(x, WT1, dinv, h1, n);
    k_agg128<<<(n + 3) / 4, 256, 0, stream>>>(h1, rp, esrc, dinv, b1, g1, n);
    k_gemm_mfma<64, _Float16> <<<gb, 256, 0, stream>>>(g1, WT2, dinv, h2, n);
    k_agg64 <<<(n + 3) / 4, 256, 0, stream>>>(h2, rp, esrc, dinv, b2, out, n);
}

// Round 7
// 210.027 us; speedup vs baseline: 1.2646x; 1.2646x over previous
//
#include <hip/hip_runtime.h>
#include <stdint.h>

// ---------------------------------------------------------------------------
// GCN 2-layer encoder.  dinv[v] = 1/sqrt(1+indeg(v));
//   Agg(H)[v] = dinv[v] * ( sum_{(r->v)} dinv[r]*H[r] + dinv[v]*H[v] )
// GEMM outputs are pre-scaled by dinv[row]; edge stream stores ONLY the
// 16-bit source id.  CSR build = 2-level bucket sort, heavy atomics in LDS:
//   bhist -> bscan -> bin(chunk-reserved) -> bucket(per-bucket LDS sort)
// ---------------------------------------------------------------------------

typedef _Float16 h2v   __attribute__((ext_vector_type(2)));
typedef _Float16 h4v   __attribute__((ext_vector_type(4)));
typedef _Float16 f16x8 __attribute__((ext_vector_type(8)));
typedef float    f32x4 __attribute__((ext_vector_type(4)));

// prep: zero bucket counters, W1/W2 -> fp16 transposed (rows = out-feature)
__global__ void k_prep(const float* __restrict__ W1, const float* __restrict__ W2,
                       _Float16* __restrict__ WT1, _Float16* __restrict__ WT2,
                       uint32_t* __restrict__ bcnt) {
    int i = blockIdx.x * blockDim.x + threadIdx.x;
    if (i < 256) bcnt[i] = 0u;
    if (i < 128 * 128) {
        int f = i >> 7, k = i & 127;
        WT1[i] = (_Float16)W1[k * 128 + f];
    }
    int j = i - 128 * 128;
    if (j >= 0 && j < 64 * 128) {
        int f = j >> 7, k = j & 127;
        WT2[j] = (_Float16)W2[k * 64 + f];
    }
}

// coarse histogram: bucket = dest >> 8, LDS-aggregated
__global__ __launch_bounds__(256)
void k_bhist(const int* __restrict__ col, uint32_t* __restrict__ bcnt, int E) {
    __shared__ uint32_t h[256];
    const int t = threadIdx.x;
    h[t] = 0u; __syncthreads();
    const int base = blockIdx.x * 4096;
#pragma unroll
    for (int k = 0; k < 16; ++k) {
        int i = base + k * 256 + t;
        if (i < E) atomicAdd(&h[__builtin_nontemporal_load(&col[i]) >> 8], 1u);
    }
    __syncthreads();
    if (h[t]) atomicAdd(&bcnt[t], h[t]);
}

// one-WG exclusive scan of bucket counts -> boff, bfill; rp[n] = E
__global__ void k_bscan(const uint32_t* __restrict__ bcnt, uint32_t* __restrict__ boff,
                        uint32_t* __restrict__ bfill, uint32_t* __restrict__ rp,
                        int NB, int n) {
    __shared__ uint32_t s[256];
    const int t = threadIdx.x;
    uint32_t v = (t < NB) ? bcnt[t] : 0u;
    s[t] = v; __syncthreads();
    for (int off = 1; off < 256; off <<= 1) {
        uint32_t u = (t >= off) ? s[t - off] : 0u;
        __syncthreads();
        s[t] += u;
        __syncthreads();
    }
    uint32_t ex = s[t] - v;
    if (t < NB) { boff[t] = ex; bfill[t] = ex; }
    if (t == NB - 1) { boff[NB] = s[t]; rp[n] = s[t]; }   // == E
}

// bin edges into bucket regions; per-WG chunk reservation -> coalescing writes
__global__ __launch_bounds__(256)
void k_bin(const int* __restrict__ row, const int* __restrict__ col,
           uint32_t* __restrict__ bfill, uint32_t* __restrict__ ebuf, int E) {
    __shared__ uint32_t hcnt[256], hbase[256];
    const int t = threadIdx.x;
    hcnt[t] = 0u; __syncthreads();
    const int base = blockIdx.x * 4096;
#pragma unroll
    for (int k = 0; k < 16; ++k) {
        int i = base + k * 256 + t;
        if (i < E) atomicAdd(&hcnt[__builtin_nontemporal_load(&col[i]) >> 8], 1u);
    }
    __syncthreads();
    hbase[t] = atomicAdd(&bfill[t], hcnt[t]);   // reserve contiguous chunk
    hcnt[t] = 0u;                                // reuse as local fill
    __syncthreads();
#pragma unroll
    for (int k = 0; k < 16; ++k) {
        int i = base + k * 256 + t;
        if (i < E) {
            int c = __builtin_nontemporal_load(&col[i]);
            int r = __builtin_nontemporal_load(&row[i]);
            int b = c >> 8;
            uint32_t slot = hbase[b] + atomicAdd(&hcnt[b], 1u);
            ebuf[slot] = (uint32_t)r | ((uint32_t)(c & 255) << 16);
        }
    }
}

// per-bucket finalize: LDS per-node count + scan -> rp, dinv, esrc(u16).
// All scatter positions within the bucket's contiguous window; LDS atomics only.
__global__ __launch_bounds__(256)
void k_bucket(const uint32_t* __restrict__ boff, const uint32_t* __restrict__ ebuf,
              uint32_t* __restrict__ rp, float* __restrict__ dinv,
              uint16_t* __restrict__ esrc, int n) {
    __shared__ uint32_t lcnt[256], lbase[256];
    const int t = threadIdx.x;
    const int b = blockIdx.x;
    const int base_c = b << 8;
    const int nc = min(256, n - base_c);
    const uint32_t start = boff[b], end = boff[b + 1];

    lcnt[t] = 0u; __syncthreads();
    for (uint32_t i = start + t; i < end; i += 256)
        atomicAdd(&lcnt[ebuf[i] >> 16], 1u);
    __syncthreads();

    const uint32_t v = lcnt[t];
    lbase[t] = v; __syncthreads();
    for (int off = 1; off < 256; off <<= 1) {
        uint32_t u = (t >= off) ? lbase[t - off] : 0u;
        __syncthreads();
        lbase[t] += u;
        __syncthreads();
    }
    const uint32_t ex = lbase[t] - v;            // exclusive within bucket
    if (t < nc) {
        rp[base_c + t]   = start + ex;
        dinv[base_c + t] = rsqrtf((float)(v + 1u));
    }
    lbase[t] = start + ex;                       // absolute base for node t
    lcnt[t]  = 0u;                               // reuse as fill
    __syncthreads();

    for (uint32_t i = start + t; i < end; i += 256) {
        uint32_t vv = ebuf[i];
        uint32_t cl = vv >> 16;
        uint32_t slot = lbase[cl] + atomicAdd(&lcnt[cl], 1u);
        esrc[slot] = (uint16_t)(vv & 0xffffu);
    }
}

// ---- MFMA GEMM: Hs[r] = fp16(dinv[r] * (X[r] @ W)), WT=[FOUT][128] fp16 ----
template <int FOUT, typename XT>
__global__ __launch_bounds__(256)
void k_gemm_mfma(const XT* __restrict__ X, const _Float16* __restrict__ WT,
                 const float* __restrict__ dinv, _Float16* __restrict__ H, int n) {
    constexpr int K  = 128;
    constexpr int KP = K + 8;           // pad -> conflict-free ds_read_b128
    constexpr int NT = FOUT / 16;
    __shared__ _Float16 Wl[FOUT * KP];

    const int tid = threadIdx.x;
    for (int i = tid; i < FOUT * (K / 8); i += 256) {
        int f = i / (K / 8), kc = i % (K / 8);
        *reinterpret_cast<f16x8*>(&Wl[f * KP + kc * 8]) =
            *reinterpret_cast<const f16x8*>(&WT[f * K + kc * 8]);
    }
    __syncthreads();

    const int wid  = tid >> 6;
    const int lane = tid & 63;
    const int col  = lane & 15;         // node within 16-tile
    const int krow = lane >> 4;         // k-chunk selector (0..3)
    const int node = blockIdx.x * 64 + wid * 16 + col;
    const int nld  = node < n ? node : n - 1;

    f32x4 acc[NT];
#pragma unroll
    for (int t = 0; t < NT; ++t) acc[t] = (f32x4){0.f, 0.f, 0.f, 0.f};

#pragma unroll
    for (int ks = 0; ks < 4; ++ks) {
        const int k0 = ks * 32 + krow * 8;
        f16x8 b;
        if constexpr (sizeof(XT) == 4) {
            float4 x0 = *reinterpret_cast<const float4*>(&X[(size_t)nld * K + k0]);
            float4 x1 = *reinterpret_cast<const float4*>(&X[(size_t)nld * K + k0 + 4]);
            b[0] = (_Float16)x0.x; b[1] = (_Float16)x0.y;
            b[2] = (_Float16)x0.z; b[3] = (_Float16)x0.w;
            b[4] = (_Float16)x1.x; b[5] = (_Float16)x1.y;
            b[6] = (_Float16)x1.z; b[7] = (_Float16)x1.w;
        } else {
            b = *reinterpret_cast<const f16x8*>(&X[(size_t)nld * K + k0]);
        }
#pragma unroll
        for (int t = 0; t < NT; ++t) {
            f16x8 a = *reinterpret_cast<const f16x8*>(&Wl[(t * 16 + col) * KP + k0]);
            acc[t] = __builtin_amdgcn_mfma_f32_16x16x32_f16(a, b, acc[t], 0, 0, 0);
        }
    }

    if (node < n) {
        const float dv = dinv[node];
#pragma unroll
        for (int t = 0; t < NT; ++t) {
            h4v hv;
            hv.x = (_Float16)(acc[t][0] * dv);
            hv.y = (_Float16)(acc[t][1] * dv);
            hv.z = (_Float16)(acc[t][2] * dv);
            hv.w = (_Float16)(acc[t][3] * dv);
            *reinterpret_cast<h4v*>(&H[(size_t)node * FOUT + t * 16 + krow * 4]) = hv;
        }
    }
}

// ---- pull agg F=128: g1 = fp16(relu(dinv[v]*(Σ Hs[src] + Hs[v]) + b1)) ----
__global__ void k_agg128(const _Float16* __restrict__ H, const uint32_t* __restrict__ rp,
                         const uint16_t* __restrict__ es, const float* __restrict__ dinv,
                         const float* __restrict__ bias, _Float16* __restrict__ out, int n) {
    int wave = (blockIdx.x * blockDim.x + threadIdx.x) >> 6;
    int lane = threadIdx.x & 63;
    if (wave >= n) return;
    const int v = wave;
    int p = (int)rp[v];
    const int e = (int)rp[v + 1];
    const int c0 = lane * 2;

    float ax = 0.f, ay = 0.f;
    for (; p + 8 <= e; p += 8) {
        int ss[8];
#pragma unroll
        for (int u = 0; u < 8; ++u) ss[u] = (int)__builtin_nontemporal_load(&es[p + u]);
        h2v hh[8];
#pragma unroll
        for (int u = 0; u < 8; ++u)
            hh[u] = *reinterpret_cast<const h2v*>(&H[(size_t)ss[u] * 128 + c0]);
#pragma unroll
        for (int u = 0; u < 8; ++u) { ax += (float)hh[u].x; ay += (float)hh[u].y; }
    }
    if (p + 4 <= e) {
        int ss[4];
#pragma unroll
        for (int u = 0; u < 4; ++u) ss[u] = (int)__builtin_nontemporal_load(&es[p + u]);
        h2v hh[4];
#pragma unroll
        for (int u = 0; u < 4; ++u)
            hh[u] = *reinterpret_cast<const h2v*>(&H[(size_t)ss[u] * 128 + c0]);
#pragma unroll
        for (int u = 0; u < 4; ++u) { ax += (float)hh[u].x; ay += (float)hh[u].y; }
        p += 4;
    }
    for (; p < e; ++p) {
        int s = (int)__builtin_nontemporal_load(&es[p]);
        h2v h0 = *reinterpret_cast<const h2v*>(&H[(size_t)s * 128 + c0]);
        ax += (float)h0.x; ay += (float)h0.y;
    }
    // self loop (pre-scaled row) + epilogue
    h2v sv = *reinterpret_cast<const h2v*>(&H[(size_t)v * 128 + c0]);
    ax += (float)sv.x; ay += (float)sv.y;
    const float dv = dinv[v];
    ax = fmaxf(fmaf(dv, ax, bias[c0]), 0.f);
    ay = fmaxf(fmaf(dv, ay, bias[c0 + 1]), 0.f);
    h2v o; o.x = (_Float16)ax; o.y = (_Float16)ay;
    *reinterpret_cast<h2v*>(&out[(size_t)v * 128 + c0]) = o;
}

// ---- pull agg F=64: two 32-lane halves, stride-2 edges, fp32 out ----
__global__ void k_agg64(const _Float16* __restrict__ H, const uint32_t* __restrict__ rp,
                        const uint16_t* __restrict__ es, const float* __restrict__ dinv,
                        const float* __restrict__ bias, float* __restrict__ out, int n) {
    int wave = (blockIdx.x * blockDim.x + threadIdx.x) >> 6;
    int lane = threadIdx.x & 63;
    if (wave >= n) return;
    const int v = wave;
    const int half = lane >> 5;
    const int c0 = (lane & 31) * 2;
    int p = (int)rp[v] + half;
    const int e = (int)rp[v + 1];

    float ax = 0.f, ay = 0.f;
    for (; p + 6 < e; p += 8) {      // edges p, p+2, p+4, p+6 for this half
        int ss[4];
#pragma unroll
        for (int u = 0; u < 4; ++u) ss[u] = (int)__builtin_nontemporal_load(&es[p + 2 * u]);
        h2v hh[4];
#pragma unroll
        for (int u = 0; u < 4; ++u)
            hh[u] = *reinterpret_cast<const h2v*>(&H[(size_t)ss[u] * 64 + c0]);
#pragma unroll
        for (int u = 0; u < 4; ++u) { ax += (float)hh[u].x; ay += (float)hh[u].y; }
    }
    for (; p < e; p += 2) {
        int s = (int)__builtin_nontemporal_load(&es[p]);
        h2v h0 = *reinterpret_cast<const h2v*>(&H[(size_t)s * 64 + c0]);
        ax += (float)h0.x; ay += (float)h0.y;
    }
    ax += __shfl_xor(ax, 32);
    ay += __shfl_xor(ay, 32);
    if (lane < 32) {
        h2v sv = *reinterpret_cast<const h2v*>(&H[(size_t)v * 64 + c0]);
        ax += (float)sv.x; ay += (float)sv.y;
        const float dv = dinv[v];
        ax = fmaf(dv, ax, bias[c0]);
        ay = fmaf(dv, ay, bias[c0 + 1]);
        *reinterpret_cast<float2*>(&out[(size_t)v * 64 + c0]) = make_float2(ax, ay);
    }
}

extern "C" void kernel_launch(void* const* d_in, const int* in_sizes, int n_in,
                              void* d_out, int out_size, void* d_ws, size_t ws_size,
                              hipStream_t stream) {
    const float* x  = (const float*)d_in[0];
    const int*   ei = (const int*)d_in[1];
    const float* W1 = (const float*)d_in[2];
    const float* b1 = (const float*)d_in[3];
    const float* W2 = (const float*)d_in[4];
    const float* b2 = (const float*)d_in[5];
    float* out = (float*)d_out;

    const int hidden = in_sizes[3];                 // 128
    const int fin    = in_sizes[2] / hidden;        // 128
    const int n      = in_sizes[0] / fin;           // 50000 (< 65536: u16 ids)
    const int E      = in_sizes[1] / 2;             // 800000
    const int* rowi = ei;                           // edge_index[0] = sources
    const int* coli = ei + E;                       // edge_index[1] = targets
    (void)n_in; (void)out_size; (void)ws_size;

    char* ws = (char*)d_ws;
    size_t off = 0;
    auto alloc = [&](size_t bytes) -> void* {
        off = (off + 255) & ~(size_t)255;
        void* p = ws + off;
        off += bytes;
        return p;
    };
    uint32_t*  bcnt = (uint32_t*) alloc(256 * 4);
    uint32_t*  boff = (uint32_t*) alloc(257 * 4);
    uint32_t*  bfill= (uint32_t*) alloc(256 * 4);
    uint32_t*  rp   = (uint32_t*) alloc((size_t)(n + 1) * 4);
    float*     dinv = (float*)    alloc((size_t)n * 4);
    uint32_t*  ebuf = (uint32_t*) alloc((size_t)E * 4);
    uint16_t*  esrc = (uint16_t*) alloc((size_t)E * 2);
    _Float16*  h1   = (_Float16*) alloc((size_t)n * 128 * 2);  // reused as h2
    _Float16*  g1   = (_Float16*) alloc((size_t)n * 128 * 2);
    _Float16*  WT1  = (_Float16*) alloc(128 * 128 * 2);
    _Float16*  WT2  = (_Float16*) alloc(64 * 128 * 2);
    _Float16*  h2   = h1;

    const int nb256 = (n + 255) / 256;
    const int NB    = (n + 255) >> 8;        // 196 buckets (<= 256 for n<65536)
    const int NW    = (E + 4095) >> 12;      // 196 binning WGs

    k_prep  <<<nb256, 256, 0, stream>>>(W1, W2, WT1, WT2, bcnt);
    k_bhist <<<NW, 256, 0, stream>>>(coli, bcnt, E);
    k_bscan <<<1, 256, 0, stream>>>(bcnt, boff, bfill, rp, NB, n);
    k_bin   <<<NW, 256, 0, stream>>>(rowi, coli, bfill, ebuf, E);
    k_bucket<<<NB, 256, 0, stream>>>(boff, ebuf, rp, dinv, esrc, n);

    const int gb = (n + 63) / 64;
    k_gemm_mfma<128, float>   <<<gb, 256, 0, stream>>>(x, WT1, dinv, h1, n);
    k_agg128<<<(n + 3) / 4, 256, 0, stream>>>(h1, rp, esrc, dinv, b1, g1, n);
    k_gemm_mfma<64, _Float16> <<<gb, 256, 0, stream>>>(g1, WT2, dinv, h2, n);
    k_agg64 <<<(n + 3) / 4, 256, 0, stream>>>(h2, rp, esrc, dinv, b2, out, n);
}

// Round 10
// 197.058 us; speedup vs baseline: 1.3478x; 1.0658x over previous
//
#include <hip/hip_runtime.h>
#include <stdint.h>

// ---------------------------------------------------------------------------
// GCN 2-layer encoder.  dinv[v] = 1/sqrt(1+indeg(v));
//   Agg(H)[v] = dinv[v] * ( sum_{(r->v)} dinv[r]*H[r] + dinv[v]*H[v] )
// GEMM outputs pre-scaled by dinv[row]; edge stream = 16-bit source ids in a
// dest-CSR PADDED to 8-edge multiples with sentinel src=n (H row n is zero)
// -> 16B-aligned dwordx4 id loads, tail-free unroll-16 gather loops.
// Per-node ranges stored as explicit [rps, rpe) (buckets are NOT contiguous).
// Layer-2 GEMM (128->64) fused into the layer-1 aggregation epilogue.
// CSR build = 2-level bucket sort, heavy atomics in LDS only.
// ---------------------------------------------------------------------------

typedef _Float16 h2v   __attribute__((ext_vector_type(2)));
typedef _Float16 h4v   __attribute__((ext_vector_type(4)));
typedef _Float16 f16x8 __attribute__((ext_vector_type(8)));
typedef float    f32x4 __attribute__((ext_vector_type(4)));

// prep: zero bucket counters + sentinel rows; W1 -> fp16 transposed WT1;
// W2 -> fp16 pair-packed W2P[k2][f] = (W2[2k2][f], W2[2k2+1][f])
__global__ void k_prep(const float* __restrict__ W1, const float* __restrict__ W2,
                       _Float16* __restrict__ WT1, h2v* __restrict__ W2P,
                       uint32_t* __restrict__ bcnt,
                       _Float16* __restrict__ h1, _Float16* __restrict__ h2, int n) {
    int i = blockIdx.x * blockDim.x + threadIdx.x;   // 0..16383
    if (i < 256) bcnt[i] = 0u;
    if (i < 128) h1[(size_t)n * 128 + i] = (_Float16)0.f;
    if (i < 64)  h2[(size_t)n * 64  + i] = (_Float16)0.f;
    if (i < 128 * 128) {
        int f = i >> 7, k = i & 127;
        WT1[i] = (_Float16)W1[k * 128 + f];
    }
    if (i < 4096) {
        int k2 = i >> 6, f = i & 63;
        h2v pr;
        pr.x = (_Float16)W2[(2 * k2) * 64 + f];
        pr.y = (_Float16)W2[(2 * k2 + 1) * 64 + f];
        W2P[i] = pr;
    }
}

// coarse histogram: bucket = dest >> 8, LDS-aggregated
__global__ __launch_bounds__(256)
void k_bhist(const int* __restrict__ col, uint32_t* __restrict__ bcnt, int E) {
    __shared__ uint32_t h[256];
    const int t = threadIdx.x;
    h[t] = 0u; __syncthreads();
    const int base = blockIdx.x * 4096;
#pragma unroll
    for (int k = 0; k < 16; ++k) {
        int i = base + k * 256 + t;
        if (i < E) atomicAdd(&h[__builtin_nontemporal_load(&col[i]) >> 8], 1u);
    }
    __syncthreads();
    if (h[t]) atomicAdd(&bcnt[t], h[t]);
}

// one-WG exclusive scan of bucket counts -> boff, bfill
__global__ void k_bscan(const uint32_t* __restrict__ bcnt, uint32_t* __restrict__ boff,
                        uint32_t* __restrict__ bfill, int NB) {
    __shared__ uint32_t s[256];
    const int t = threadIdx.x;
    uint32_t v = (t < NB) ? bcnt[t] : 0u;
    s[t] = v; __syncthreads();
    for (int off = 1; off < 256; off <<= 1) {
        uint32_t u = (t >= off) ? s[t - off] : 0u;
        __syncthreads();
        s[t] += u;
        __syncthreads();
    }
    uint32_t ex = s[t] - v;
    if (t < NB) { boff[t] = ex; bfill[t] = ex; }
    if (t == NB - 1) boff[NB] = s[t];
}

// bin edges into bucket regions; per-WG chunk reservation -> coalescing writes
__global__ __launch_bounds__(256)
void k_bin(const int* __restrict__ row, const int* __restrict__ col,
           uint32_t* __restrict__ bfill, uint32_t* __restrict__ ebuf, int E) {
    __shared__ uint32_t hcnt[256], hbase[256];
    const int t = threadIdx.x;
    hcnt[t] = 0u; __syncthreads();
    const int base = blockIdx.x * 4096;
#pragma unroll
    for (int k = 0; k < 16; ++k) {
        int i = base + k * 256 + t;
        if (i < E) atomicAdd(&hcnt[__builtin_nontemporal_load(&col[i]) >> 8], 1u);
    }
    __syncthreads();
    hbase[t] = atomicAdd(&bfill[t], hcnt[t]);   // reserve contiguous chunk
    hcnt[t] = 0u;                                // reuse as local fill
    __syncthreads();
#pragma unroll
    for (int k = 0; k < 16; ++k) {
        int i = base + k * 256 + t;
        if (i < E) {
            int c = __builtin_nontemporal_load(&col[i]);
            int r = __builtin_nontemporal_load(&row[i]);
            int b = c >> 8;
            uint32_t slot = hbase[b] + atomicAdd(&hcnt[b], 1u);
            ebuf[slot] = (uint32_t)r | ((uint32_t)(c & 255) << 16);
        }
    }
}

// per-bucket finalize: LDS count + PADDED scan -> rps/rpe (8-aligned), dinv,
// esrc windows pre-filled with sentinel n, then LDS-atomic scatter.
__global__ __launch_bounds__(256)
void k_bucket(const uint32_t* __restrict__ boff, const uint32_t* __restrict__ ebuf,
              uint32_t* __restrict__ rps, uint32_t* __restrict__ rpe,
              float* __restrict__ dinv, uint16_t* __restrict__ esrc, int n) {
    __shared__ uint32_t lcnt[256], lscan[256], lbase[256], lfill[256];
    __shared__ uint32_t s_total;
    const int t = threadIdx.x;
    const int b = blockIdx.x;
    const int base_c = b << 8;
    const int nc = min(256, n - base_c);
    const uint32_t start = boff[b], end = boff[b + 1];
    const uint32_t pstart = (start + (uint32_t)b * 2048u + 7u) & ~7u;

    lcnt[t] = 0u; __syncthreads();
    for (uint32_t i = start + t; i < end; i += 256)
        atomicAdd(&lcnt[ebuf[i] >> 16], 1u);
    __syncthreads();

    const uint32_t v  = lcnt[t];
    const uint32_t pc = (v + 7u) & ~7u;          // padded count (mult of 8)
    lscan[t] = pc; __syncthreads();
    for (int off = 1; off < 256; off <<= 1) {    // inclusive scan of pc
        uint32_t u = (t >= off) ? lscan[t - off] : 0u;
        __syncthreads();
        lscan[t] += u;
        __syncthreads();
    }
    const uint32_t pex = lscan[t] - pc;          // padded exclusive
    if (t == 255) s_total = lscan[255];
    if (t < nc) {
        rps[base_c + t]  = pstart + pex;
        rpe[base_c + t]  = pstart + pex + pc;    // exact end (gap-safe)
        dinv[base_c + t] = rsqrtf((float)(v + 1u));
    }
    lbase[t] = pstart + pex;
    lfill[t] = 0u;
    __syncthreads();
    const uint32_t total = s_total;
    for (uint32_t i = t; i < total; i += 256)    // sentinel pre-fill
        esrc[pstart + i] = (uint16_t)n;
    __syncthreads();
    for (uint32_t i = start + t; i < end; i += 256) {
        uint32_t vv = ebuf[i];
        uint32_t cl = vv >> 16;
        uint32_t slot = lbase[cl] + atomicAdd(&lfill[cl], 1u);
        esrc[slot] = (uint16_t)(vv & 0xffffu);
    }
}

// ---- MFMA GEMM: h1s[r] = fp16(dinv[r] * (X[r] @ W1)), WT=[128][128] fp16 ----
template <int FOUT, typename XT>
__global__ __launch_bounds__(256)
void k_gemm_mfma(const XT* __restrict__ X, const _Float16* __restrict__ WT,
                 const float* __restrict__ dinv, _Float16* __restrict__ H, int n) {
    constexpr int K  = 128;
    constexpr int KP = K + 8;           // pad -> conflict-free ds_read_b128
    constexpr int NT = FOUT / 16;
    __shared__ _Float16 Wl[FOUT * KP];

    const int tid = threadIdx.x;
    for (int i = tid; i < FOUT * (K / 8); i += 256) {
        int f = i / (K / 8), kc = i % (K / 8);
        *reinterpret_cast<f16x8*>(&Wl[f * KP + kc * 8]) =
            *reinterpret_cast<const f16x8*>(&WT[f * K + kc * 8]);
    }
    __syncthreads();

    const int wid  = tid >> 6;
    const int lane = tid & 63;
    const int col  = lane & 15;
    const int krow = lane >> 4;
    const int node = blockIdx.x * 64 + wid * 16 + col;
    const int nld  = node < n ? node : n - 1;

    f32x4 acc[NT];
#pragma unroll
    for (int t = 0; t < NT; ++t) acc[t] = (f32x4){0.f, 0.f, 0.f, 0.f};

#pragma unroll
    for (int ks = 0; ks < 4; ++ks) {
        const int k0 = ks * 32 + krow * 8;
        f16x8 b;
        if constexpr (sizeof(XT) == 4) {
            float4 x0 = *reinterpret_cast<const float4*>(&X[(size_t)nld * K + k0]);
            float4 x1 = *reinterpret_cast<const float4*>(&X[(size_t)nld * K + k0 + 4]);
            b[0] = (_Float16)x0.x; b[1] = (_Float16)x0.y;
            b[2] = (_Float16)x0.z; b[3] = (_Float16)x0.w;
            b[4] = (_Float16)x1.x; b[5] = (_Float16)x1.y;
            b[6] = (_Float16)x1.z; b[7] = (_Float16)x1.w;
        } else {
            b = *reinterpret_cast<const f16x8*>(&X[(size_t)nld * K + k0]);
        }
#pragma unroll
        for (int t = 0; t < NT; ++t) {
            f16x8 a = *reinterpret_cast<const f16x8*>(&Wl[(t * 16 + col) * KP + k0]);
            acc[t] = __builtin_amdgcn_mfma_f32_16x16x32_f16(a, b, acc[t], 0, 0, 0);
        }
    }

    if (node < n) {
        const float dv = dinv[node];
#pragma unroll
        for (int t = 0; t < NT; ++t) {
            h4v hv;
            hv.x = (_Float16)(acc[t][0] * dv);
            hv.y = (_Float16)(acc[t][1] * dv);
            hv.z = (_Float16)(acc[t][2] * dv);
            hv.w = (_Float16)(acc[t][3] * dv);
            *reinterpret_cast<h4v*>(&H[(size_t)node * FOUT + t * 16 + krow * 4]) = hv;
        }
    }
}

// ---- fused: g1[v] = relu(dinv*(Σ h1s[src] + h1s[v]) + b1)  (in regs/LDS)
//             h2s[v] = fp16(dinv[v] * (g1[v] @ W2))           (128 -> 64 dot)
__global__ __launch_bounds__(256)
void k_aggmm(const _Float16* __restrict__ H, const uint32_t* __restrict__ rps,
             const uint32_t* __restrict__ rpe, const uint16_t* __restrict__ es,
             const float* __restrict__ dinv, const float* __restrict__ b1,
             const h2v* __restrict__ W2P, _Float16* __restrict__ h2out, int n) {
    __shared__ h2v   W2l[64 * 64];       // 16 KB, pair-packed [k2][f]
    __shared__ float2 g1row[4][64];      // per-wave g1 feature pairs
    const int tid = threadIdx.x;
    for (int i = tid; i < 1024; i += 256)
        reinterpret_cast<uint4*>(W2l)[i] = reinterpret_cast<const uint4*>(W2P)[i];
    __syncthreads();

    const int wid = tid >> 6, lane = tid & 63;
    const int v = blockIdx.x * 4 + wid;
    if (v >= n) return;
    const int c0 = lane * 2;
    int p = (int)rps[v];
    const int e = (int)rpe[v];           // (e - p) is a multiple of 8

    float ax = 0.f, ay = 0.f;
    for (; p + 16 <= e; p += 16) {
        uint4 wa = *reinterpret_cast<const uint4*>(&es[p]);
        uint4 wb = *reinterpret_cast<const uint4*>(&es[p + 8]);
        uint32_t id[16] = { wa.x & 0xffffu, wa.x >> 16, wa.y & 0xffffu, wa.y >> 16,
                            wa.z & 0xffffu, wa.z >> 16, wa.w & 0xffffu, wa.w >> 16,
                            wb.x & 0xffffu, wb.x >> 16, wb.y & 0xffffu, wb.y >> 16,
                            wb.z & 0xffffu, wb.z >> 16, wb.w & 0xffffu, wb.w >> 16 };
        h2v hh[16];
#pragma unroll
        for (int u = 0; u < 16; ++u)
            hh[u] = *reinterpret_cast<const h2v*>(&H[(size_t)id[u] * 128 + c0]);
#pragma unroll
        for (int u = 0; u < 16; ++u) { ax += (float)hh[u].x; ay += (float)hh[u].y; }
    }
    if (p < e) {                          // exactly one 8-block remains
        uint4 wa = *reinterpret_cast<const uint4*>(&es[p]);
        uint32_t id[8] = { wa.x & 0xffffu, wa.x >> 16, wa.y & 0xffffu, wa.y >> 16,
                           wa.z & 0xffffu, wa.z >> 16, wa.w & 0xffffu, wa.w >> 16 };
        h2v hh[8];
#pragma unroll
        for (int u = 0; u < 8; ++u)
            hh[u] = *reinterpret_cast<const h2v*>(&H[(size_t)id[u] * 128 + c0]);
#pragma unroll
        for (int u = 0; u < 8; ++u) { ax += (float)hh[u].x; ay += (float)hh[u].y; }
    }
    // self row + layer-1 epilogue
    h2v sv = *reinterpret_cast<const h2v*>(&H[(size_t)v * 128 + c0]);
    ax += (float)sv.x; ay += (float)sv.y;
    const float dv = dinv[v];
    float gx = fmaxf(fmaf(dv, ax, b1[c0]), 0.f);
    float gy = fmaxf(fmaf(dv, ay, b1[c0 + 1]), 0.f);
    g1row[wid][lane] = make_float2(gx, gy);   // same-wave DS ops are in-order

    // 128 -> 64 dot: lane = output feature
    float acc = 0.f;
#pragma unroll 8
    for (int k2 = 0; k2 < 64; ++k2) {
        float2 g = g1row[wid][k2];            // broadcast read
        h2v w = W2l[k2 * 64 + lane];          // stride-1, conflict-free
        acc += g.x * (float)w.x + g.y * (float)w.y;
    }
    h2out[(size_t)v * 64 + lane] = (_Float16)(dv * acc);
}

// ---- pull agg F=64: two 32-lane halves alternate 8-blocks, fp32 out ----
__global__ __launch_bounds__(256)
void k_agg64(const _Float16* __restrict__ H, const uint32_t* __restrict__ rps,
             const uint32_t* __restrict__ rpe, const uint16_t* __restrict__ es,
             const float* __restrict__ dinv, const float* __restrict__ bias,
             float* __restrict__ out, int n) {
    int wave = (blockIdx.x * blockDim.x + threadIdx.x) >> 6;
    int lane = threadIdx.x & 63;
    if (wave >= n) return;
    const int v = wave;
    const int half = lane >> 5;
    const int c0 = (lane & 31) * 2;
    int p = (int)rps[v] + half * 8;
    const int e = (int)rpe[v];

    float ax = 0.f, ay = 0.f;
    for (; p + 8 <= e; p += 16) {
        uint4 wa = *reinterpret_cast<const uint4*>(&es[p]);
        uint32_t id[8] = { wa.x & 0xffffu, wa.x >> 16, wa.y & 0xffffu, wa.y >> 16,
                           wa.z & 0xffffu, wa.z >> 16, wa.w & 0xffffu, wa.w >> 16 };
        h2v hh[8];
#pragma unroll
        for (int u = 0; u < 8; ++u)
            hh[u] = *reinterpret_cast<const h2v*>(&H[(size_t)id[u] * 64 + c0]);
#pragma unroll
        for (int u = 0; u < 8; ++u) { ax += (float)hh[u].x; ay += (float)hh[u].y; }
    }
    ax += __shfl_xor(ax, 32);
    ay += __shfl_xor(ay, 32);
    if (lane < 32) {
        h2v sv = *reinterpret_cast<const h2v*>(&H[(size_t)v * 64 + c0]);
        ax += (float)sv.x; ay += (float)sv.y;
        const float dv = dinv[v];
        ax = fmaf(dv, ax, bias[c0]);
        ay = fmaf(dv, ay, bias[c0 + 1]);
        *reinterpret_cast<float2*>(&out[(size_t)v * 64 + c0]) = make_float2(ax, ay);
    }
}

extern "C" void kernel_launch(void* const* d_in, const int* in_sizes, int n_in,
                              void* d_out, int out_size, void* d_ws, size_t ws_size,
                              hipStream_t stream) {
    const float* x  = (const float*)d_in[0];
    const int*   ei = (const int*)d_in[1];
    const float* W1 = (const float*)d_in[2];
    const float* b1 = (const float*)d_in[3];
    const float* W2 = (const float*)d_in[4];
    const float* b2 = (const float*)d_in[5];
    float* out = (float*)d_out;

    const int hidden = in_sizes[3];                 // 128
    const int fin    = in_sizes[2] / hidden;        // 128
    const int n      = in_sizes[0] / fin;           // 50000 (< 65536: u16 ids)
    const int E      = in_sizes[1] / 2;             // 800000
    const int* rowi = ei;                           // edge_index[0] = sources
    const int* coli = ei + E;                       // edge_index[1] = targets
    (void)n_in; (void)out_size; (void)ws_size;

    char* ws = (char*)d_ws;
    size_t off = 0;
    auto alloc = [&](size_t bytes) -> void* {
        off = (off + 255) & ~(size_t)255;
        void* p = ws + off;
        off += bytes;
        return p;
    };
    const int NB = (n + 255) >> 8;                   // 196 buckets
    uint32_t*  bcnt = (uint32_t*) alloc(256 * 4);
    uint32_t*  boff = (uint32_t*) alloc(257 * 4);
    uint32_t*  bfill= (uint32_t*) alloc(256 * 4);
    uint32_t*  rps  = (uint32_t*) alloc((size_t)n * 4);
    uint32_t*  rpe  = (uint32_t*) alloc((size_t)n * 4);
    float*     dinv = (float*)    alloc((size_t)n * 4);
    uint32_t*  ebuf = (uint32_t*) alloc((size_t)E * 4);
    uint16_t*  esrc = (uint16_t*) alloc(((size_t)E + (size_t)NB * 2048 + 4096) * 2);
    _Float16*  h1   = (_Float16*) alloc((size_t)(n + 1) * 128 * 2);
    _Float16*  h2   = (_Float16*) alloc((size_t)(n + 1) * 64 * 2);
    _Float16*  WT1  = (_Float16*) alloc(128 * 128 * 2);
    h2v*       W2P  = (h2v*)      alloc(64 * 64 * sizeof(h2v));

    const int NW = (E + 4095) >> 12;                 // 196 binning WGs

    k_prep  <<<64, 256, 0, stream>>>(W1, W2, WT1, W2P, bcnt, h1, h2, n);
    k_bhist <<<NW, 256, 0, stream>>>(coli, bcnt, E);
    k_bscan <<<1, 256, 0, stream>>>(bcnt, boff, bfill, NB);
    k_bin   <<<NW, 256, 0, stream>>>(rowi, coli, bfill, ebuf, E);
    k_bucket<<<NB, 256, 0, stream>>>(boff, ebuf, rps, rpe, dinv, esrc, n);

    const int gb = (n + 63) / 64;
    k_gemm_mfma<128, float><<<gb, 256, 0, stream>>>(x, WT1, dinv, h1, n);
    k_aggmm <<<(n + 3) / 4, 256, 0, stream>>>(h1, rps, rpe, esrc, dinv, b1, W2P, h2, n);
    k_agg64 <<<(n + 3) / 4, 256, 0, stream>>>(h2, rps, rpe, esrc, dinv, b2, out, n);
}